// Round 17
// baseline (6570.029 us; speedup 1.0000x reference)
//
#include <hip/hip_runtime.h>
#include <hip/hip_bf16.h>

#define TT 3650
#define HH 256

typedef _Float16 f16x4 __attribute__((ext_vector_type(4)));
typedef _Float16 f16x8 __attribute__((ext_vector_type(8)));
typedef float f32x4 __attribute__((ext_vector_type(4)));

__device__ __forceinline__ float xexp2(float x) { return __builtin_amdgcn_exp2f(x); }
__device__ __forceinline__ float xrcp(float x) { return __builtin_amdgcn_rcpf(x); }
__device__ __forceinline__ float xexp(float x) { return xexp2(x * 1.4426950408889634f); }
__device__ __forceinline__ float xtanh(float x) {
  float e = xexp2(x * 2.8853900817779268f);  // e^{2x}
  return 1.0f - 2.0f * xrcp(e + 1.0f);
}
// tanh(d * 2^-10): descale fused into the exp2 constant
__device__ __forceinline__ float xtanh_ds(float d) {
  float e = xexp2(d * 0.0028177637517362566f);  // 2.88539../1024
  return 1.0f - 2.0f * xrcp(e + 1.0f);
}
__device__ __forceinline__ float xstep(float x) {  // sigmoid(10x)
  return xrcp(1.0f + xexp2(-14.426950408889634f * x));
}
__device__ __forceinline__ float xsinh(float x) {
  float e = xexp(x);
  return 0.5f * (e - xrcp(e));
}

#define DPPADD(x, ctrl)                                                        \
  (x) += __builtin_bit_cast(float, __builtin_amdgcn_update_dpp(                \
            0, __builtin_bit_cast(int, (x)), (ctrl), 0xf, 0xf, false));
#define RDLANE(x, l)                                                           \
  __builtin_bit_cast(float,                                                    \
      __builtin_amdgcn_readlane(__builtin_bit_cast(int, (x)), (l)))

#define REPC(M) M(0) M(1) M(2) M(3)

// Weights stored as fp16 of (W * 2^10): avoids fp16-denormal weights, which
// the MFMA pipe flushes (round-9 drift). Descale fused into xtanh_ds.
#define WSCALE 1024.0f

#define SF_PAD 2

// 8 waves = 2/SIMD via K-SPLIT: wave (jg=w&3, kh=w>>2) owns 64 j's x half-K.
// CU totals unchanged vs r14 (256 MFMA, 64 av-reads) but each SIMD now has a
// second wave to overlap VALU/DS/latency with MFMA issue (r16 analysis: the
// pipes were ~fully serialized at 1 wave/SIMD; sum ~= measured step).
// Cost: z-partial exchange (2 extra barriers). Fit: 128 AGPR + ~110 arch VGPR
// per wave <= 256 at 2 waves/EU (__launch_bounds__(512, 2)).
__global__ void __launch_bounds__(512, 2) exphydro_scan(
    const float* __restrict__ gin, const float* __restrict__ gdayl,
    const float* __restrict__ gW0, const float* __restrict__ gb0,
    const float* __restrict__ gW1, const float* __restrict__ gb1,
    const float* __restrict__ gW2, const float* __restrict__ gb2,
    const float* __restrict__ gWout, const float* __restrict__ gbout,
    float* __restrict__ gout) {
  __shared__ alignas(16) _Float16 h0l[HH];   // 512 B activation buffers
  __shared__ alignas(16) _Float16 h1l[HH];
  __shared__ f32x4 sZ[8][16];                // z-partial exchange, 2 KB
  __shared__ float sWP[64];                  // [m][jg]: slot m*4+jg, 20 used
  __shared__ f32x4 sF[TT + SF_PAD];          // packed forcings {p,tm,ld,0}
  // Output buffers in LDS (r14 win): no global stores in-loop.
  __shared__ float sQ[TT], sS0[TT], sS1[TT];

  const int tid = threadIdx.x;
  const int lane = tid & 63;
  const int w = tid >> 6;          // wave 0..7
  const int jg = w & 3;            // j-group
  const int kh = w >> 2;           // k-half
  const int li = lane & 15;        // MFMA col within tile
  const int g = lane >> 4;         // k-subgroup 0..3
  const int jb = 64 * jg + 4 * li; // this lane's 4 MFMA j's: jb+0..3
  const int j0 = tid & 255;        // this thread's layer-0 j (kh pair shares)
  const int sib = 4 * kh;          // first k-slice of this wave's half

  // ---- stage packed forcings ----
  for (int i = tid; i < TT; i += 512) {
    f32x4 F = {gin[5 * i + 2], gin[5 * i + 3], gdayl[i], 0.0f};
    sF[i] = F;
  }
  if (tid < SF_PAD) {
    f32x4 Z = {0.f, 0.f, 0.f, 0.f};
    sF[TT + tid] = Z;
  }
  if (tid < 64) sWP[tid] = 0.0f;   // slots >=20 stay 0 forever

  // ---- per-thread constants ----
  float s0 = gin[0], s1 = gin[1];
  const float bo0 = gbout[0], bo1 = gbout[1], bo2 = gbout[2], bo3 = gbout[3],
              bo4 = gbout[4];
  // layer-0 consts (used by kh==0 waves only, but loaded uniformly)
  const float w00J = gW0[j0], w01J = gW0[HH + j0], w02J = gW0[2 * HH + j0],
              w03J = gW0[3 * HH + j0], b0J = gb0[j0];
  // per-chain consts: scaled biases ride in the kh=0 accumulator C-init
#define CDECL(c)                                                               \
  const float b1s_##c = kh ? 0.0f : gb1[jb + (c)] * WSCALE,                    \
              b2s_##c = kh ? 0.0f : gb2[jb + (c)] * WSCALE,                    \
              wo0_##c = gWout[5 * (jb + (c)) + 0],                             \
              wo1_##c = gWout[5 * (jb + (c)) + 1],                             \
              wo2_##c = gWout[5 * (jb + (c)) + 2],                             \
              wo3_##c = gWout[5 * (jb + (c)) + 3],                             \
              wo4_##c = gWout[5 * (jb + (c)) + 4];
  REPC(CDECL)
#undef CDECL

  // ---- weight B-fragments -> AGPRs. Fragment (layer L, chain c, slice i):
  // lane holds B[k][col=li], k = 32(sib+i) + 8g + e, column j = jb + c.
  // 4 slices x 4 chains x 2 layers = 32 frags = 128 AGPRs.
#define FDECL(i) f16x8 a1_0_##i, a1_1_##i, a1_2_##i, a1_3_##i,                 \
                       a2_0_##i, a2_1_##i, a2_2_##i, a2_3_##i;
  REPC(FDECL)
#undef FDECL
#define MK(dst, G, i, c)                                                       \
  {                                                                            \
    const float* p = (G) + (32 * (sib + (i)) + g * 8) * HH + jb + (c);         \
    f16x8 f;                                                                   \
    f[0] = (_Float16)(p[0] * WSCALE);      f[1] = (_Float16)(p[HH] * WSCALE);  \
    f[2] = (_Float16)(p[2 * HH] * WSCALE); f[3] = (_Float16)(p[3 * HH] * WSCALE); \
    f[4] = (_Float16)(p[4 * HH] * WSCALE); f[5] = (_Float16)(p[5 * HH] * WSCALE); \
    f[6] = (_Float16)(p[6 * HH] * WSCALE); f[7] = (_Float16)(p[7 * HH] * WSCALE); \
    dst = f;                                                                   \
    asm volatile("" : "+a"(dst));                                              \
  }
#define FINIT(i)                                                               \
  MK(a1_0_##i, gW1, i, 0) MK(a1_1_##i, gW1, i, 1)                              \
  MK(a1_2_##i, gW1, i, 2) MK(a1_3_##i, gW1, i, 3)                              \
  MK(a2_0_##i, gW2, i, 0) MK(a2_1_##i, gW2, i, 1)                              \
  MK(a2_2_##i, gW2, i, 2) MK(a2_3_##i, gW2, i, 3)
  REPC(FINIT)
#undef FINIT
#undef MK

  const char* hp0 = (const char*)h0l + g * 16;  // A-fill base (k-subgroup)
  const char* hp1 = (const char*)h1l + g * 16;

#define MFMA(acc, a, b)                                                        \
  asm("v_mfma_f32_16x16x32_f16 %0, %1, %2, %0" : "+v"(acc) : "v"(a), "a"(b));

  __syncthreads();  // staging + sWP zero visible

  f32x4 Fc = sF[0];
  for (int t = 0; t < TT; ++t) {
    const float p_in = Fc[0];
    const float tm = Fc[1];
    const float ld = Fc[2];

    // ---- layer 0: kh=0 waves compute one j per thread and write ----
    if (kh == 0) {
      float h0J = xtanh(b0J + s0 * w00J + s1 * w01J + p_in * w02J + tm * w03J);
      h0l[j0] = (_Float16)h0J;
    }
    __syncthreads();  // A: h0 ready

    f32x4 Fn = sF[t + 1];  // prefetch next forcings

    // ---- layer 1: 16 MFMA over this wave's k-half, 4 chains ----
    f32x4 d0 = {b1s_0, 0.f, 0.f, 0.f}, d1 = {b1s_1, 0.f, 0.f, 0.f};
    f32x4 d2 = {b1s_2, 0.f, 0.f, 0.f}, d3 = {b1s_3, 0.f, 0.f, 0.f};
    asm volatile("s_nop 1" : "+v"(d0), "+v"(d1), "+v"(d2), "+v"(d3));
#define MM1(i)                                                                 \
  {                                                                            \
    f16x8 av = *(const f16x8*)(hp0 + (sib + i) * 64);                          \
    MFMA(d0, av, a1_0_##i) MFMA(d1, av, a1_1_##i)                              \
    MFMA(d2, av, a1_2_##i) MFMA(d3, av, a1_3_##i)                              \
  }
    REPC(MM1)
#undef MM1
    asm volatile("s_nop 7\n\ts_nop 7" : "+v"(d0), "+v"(d1), "+v"(d2), "+v"(d3));
    // kh=1 publishes its z-partials; kh=0 will add them
    if (kh == 1 && lane < 16) {
      f32x4 zp = {d0[0], d1[0], d2[0], d3[0]};
      sZ[w][li] = zp;
    }
    __syncthreads();  // P1: partials ready
    if (kh == 0 && lane < 16) {
      f32x4 zp = sZ[w + 4][li];
      f16x4 hv = {(_Float16)xtanh_ds(d0[0] + zp[0]),
                  (_Float16)xtanh_ds(d1[0] + zp[1]),
                  (_Float16)xtanh_ds(d2[0] + zp[2]),
                  (_Float16)xtanh_ds(d3[0] + zp[3])};
      *(f16x4*)((char*)h1l + (jb << 1)) = hv;
    }
    __syncthreads();  // B: h1 ready

    // ---- layer 2 (same split) ----
    f32x4 e0 = {b2s_0, 0.f, 0.f, 0.f}, e1 = {b2s_1, 0.f, 0.f, 0.f};
    f32x4 e2 = {b2s_2, 0.f, 0.f, 0.f}, e3 = {b2s_3, 0.f, 0.f, 0.f};
    asm volatile("s_nop 1" : "+v"(e0), "+v"(e1), "+v"(e2), "+v"(e3));
#define MM2(i)                                                                 \
  {                                                                            \
    f16x8 av = *(const f16x8*)(hp1 + (sib + i) * 64);                          \
    MFMA(e0, av, a2_0_##i) MFMA(e1, av, a2_1_##i)                              \
    MFMA(e2, av, a2_2_##i) MFMA(e3, av, a2_3_##i)                              \
  }
    REPC(MM2)
#undef MM2
    asm volatile("s_nop 7\n\ts_nop 7" : "+v"(e0), "+v"(e1), "+v"(e2), "+v"(e3));
    // both halves publish; each wave adds its partner's partials
    if (lane < 16) {
      f32x4 zp = {e0[0], e1[0], e2[0], e3[0]};
      sZ[w][li] = zp;
    }
    __syncthreads();  // P2
    f32x4 zq = sZ[w ^ 4][li];  // broadcast across g
    float h2_0 = xtanh_ds(e0[0] + zq[0]);
    float h2_1 = xtanh_ds(e1[0] + zq[1]);
    float h2_2 = xtanh_ds(e2[0] + zq[2]);
    float h2_3 = xtanh_ds(e3[0] + zq[3]);

    // ---- output layer: per-lane partials over 4 j's, DPP row all-reduce ----
    float p0 = h2_0 * wo0_0 + h2_1 * wo0_1 + h2_2 * wo0_2 + h2_3 * wo0_3;
    float p1 = h2_0 * wo1_0 + h2_1 * wo1_1 + h2_2 * wo1_2 + h2_3 * wo1_3;
    float p2 = h2_0 * wo2_0 + h2_1 * wo2_1 + h2_2 * wo2_2 + h2_3 * wo2_3;
    float p3 = h2_0 * wo3_0 + h2_1 * wo3_1 + h2_2 * wo3_2 + h2_3 * wo3_3;
    float p4 = h2_0 * wo4_0 + h2_1 * wo4_1 + h2_2 * wo4_2 + h2_3 * wo4_3;
    DPPADD(p0, 0x121) DPPADD(p0, 0x122) DPPADD(p0, 0x124) DPPADD(p0, 0x128)
    DPPADD(p1, 0x121) DPPADD(p1, 0x122) DPPADD(p1, 0x124) DPPADD(p1, 0x128)
    DPPADD(p2, 0x121) DPPADD(p2, 0x122) DPPADD(p2, 0x124) DPPADD(p2, 0x128)
    DPPADD(p3, 0x121) DPPADD(p3, 0x122) DPPADD(p3, 0x124) DPPADD(p3, 0x128)
    DPPADD(p4, 0x121) DPPADD(p4, 0x122) DPPADD(p4, 0x124) DPPADD(p4, 0x128)
    // kh pairs hold identical sums; only kh=0 writes its jg's 5 partials
    float pv = lane == 0 ? p0 : lane == 1 ? p1 : lane == 2 ? p2
                                          : lane == 3 ? p3 : p4;
    if (kh == 0 && lane < 5) sWP[lane * 4 + jg] = pv;
    __syncthreads();  // C

    // ---- finalize on ALL threads: quad-xor reduce over jg, transforms ----
    float v = sWP[lane];  // lane l: m = l>>2, jg = l&3 (slots >=20 are 0)
    DPPADD(v, 0xB1)       // quad_perm xor1
    DPPADD(v, 0x4E)       // quad_perm xor2 -> quad m holds o_m
    float o0 = RDLANE(v, 0) + bo0;
    float o1 = RDLANE(v, 4) + bo1;
    float o2 = RDLANE(v, 8) + bo2;
    float o3 = RDLANE(v, 12) + bo3;
    float o4 = RDLANE(v, 16) + bo4;
    if (tid == 64) {  // one thread buffers outputs in LDS
      sQ[t] = o4;           // q_output[t] = raw mlp output m=4 at state_t
      sS0[t] = s0;          // s_snow_nn[t] (pre-update)
      sS1[t] = s1;          // s_water_nn[t]
    }
    float sh0 = xsinh(o0), sh1 = xsinh(o1), sh2 = xsinh(o2);
    float e3x = xexp(o3), e4x = xexp(o4);
    float stn = xstep(-tm), st0 = xstep(s0), st1 = xstep(s1);
    float psn = fmaxf(sh0 * stn, 0.0f);
    float prn = fmaxf(sh1, 0.0f);
    float mm = fmaxf(st0 * sh2, 0.0f);
    float evt = st1 * e3x * ld;
    float qq = st1 * e4x;
    s0 += psn - mm;                 // DT = 1
    s1 += prn + mm - evt - qq;
    Fc = Fn;
  }
#undef MFMA

  // ---- flush buffered outputs to global (coalesced) ----
  __syncthreads();
  for (int i = tid; i < TT; i += 512) {
    gout[i] = sQ[i];
    gout[TT + i] = sS0[i];
    gout[2 * TT + i] = sS1[i];
  }
}

extern "C" void kernel_launch(void* const* d_in, const int* in_sizes, int n_in,
                              void* d_out, int out_size, void* d_ws, size_t ws_size,
                              hipStream_t stream) {
  const float* gin   = (const float*)d_in[0];
  const float* gdayl = (const float*)d_in[1];
  const float* gW0   = (const float*)d_in[2];
  const float* gb0   = (const float*)d_in[3];
  const float* gW1   = (const float*)d_in[4];
  const float* gb1   = (const float*)d_in[5];
  const float* gW2   = (const float*)d_in[6];
  const float* gb2   = (const float*)d_in[7];
  const float* gWout = (const float*)d_in[8];
  const float* gbout = (const float*)d_in[9];
  float* gout = (float*)d_out;
  exphydro_scan<<<dim3(1), dim3(512), 0, stream>>>(
      gin, gdayl, gW0, gb0, gW1, gb1, gW2, gb2, gWout, gbout, gout);
}

// Round 18
// 4910.603 us; speedup vs baseline: 1.3379x; 1.3379x over previous
//
#include <hip/hip_runtime.h>
#include <hip/hip_bf16.h>

#define TT 3650
#define HH 256

typedef _Float16 f16x4 __attribute__((ext_vector_type(4)));
typedef _Float16 f16x8 __attribute__((ext_vector_type(8)));
typedef float f32x4 __attribute__((ext_vector_type(4)));

__device__ __forceinline__ float xexp2(float x) { return __builtin_amdgcn_exp2f(x); }
__device__ __forceinline__ float xrcp(float x) { return __builtin_amdgcn_rcpf(x); }
__device__ __forceinline__ float xexp(float x) { return xexp2(x * 1.4426950408889634f); }
__device__ __forceinline__ float xtanh(float x) {
  float e = xexp2(x * 2.8853900817779268f);  // e^{2x}
  return 1.0f - 2.0f * xrcp(e + 1.0f);
}
// tanh(d * 2^-10): descale fused into the exp2 constant (one mul, not two)
__device__ __forceinline__ float xtanh_ds(float d) {
  float e = xexp2(d * 0.0028177637517362566f);  // 2.88539../1024
  return 1.0f - 2.0f * xrcp(e + 1.0f);
}
__device__ __forceinline__ float xstep(float x) {  // sigmoid(10x)
  return xrcp(1.0f + xexp2(-14.426950408889634f * x));
}
__device__ __forceinline__ float xsinh(float x) {
  float e = xexp(x);
  return 0.5f * (e - xrcp(e));
}

#define DPPADD(x, ctrl)                                                        \
  (x) += __builtin_bit_cast(float, __builtin_amdgcn_update_dpp(                \
            0, __builtin_bit_cast(int, (x)), (ctrl), 0xf, 0xf, false));
#define RDLANE(x, l)                                                           \
  __builtin_bit_cast(float,                                                    \
      __builtin_amdgcn_readlane(__builtin_bit_cast(int, (x)), (l)))

#define REP8(M) M(0) M(1) M(2) M(3) M(4) M(5) M(6) M(7)
#define REPC(M) M(0) M(1) M(2) M(3)

// Weights stored as fp16 of (W * 2^10): avoids fp16-denormal weights, which
// the MFMA pipe flushes (round-9 drift). Descale fused into xtanh_ds.
#define WSCALE 1024.0f

#define SF_PAD 2

// 4 waves / 1 per SIMD (r16 structure — proven optimum): barrier-synced
// phases defeat TLP (r15: j-split doubles DS; r17: k-split adds barriers),
// so the balanced 4-wave layout with minimal DS traffic and 3 barriers wins.
__global__ void __launch_bounds__(256, 1) exphydro_scan(
    const float* __restrict__ gin, const float* __restrict__ gdayl,
    const float* __restrict__ gW0, const float* __restrict__ gb0,
    const float* __restrict__ gW1, const float* __restrict__ gb1,
    const float* __restrict__ gW2, const float* __restrict__ gb2,
    const float* __restrict__ gWout, const float* __restrict__ gbout,
    float* __restrict__ gout) {
  __shared__ alignas(16) _Float16 h0l[HH];   // 512 B activation buffers
  __shared__ alignas(16) _Float16 h1l[HH];
  __shared__ float sWP[64];                  // [m][w]: slot m*4+w, 20 used
  __shared__ f32x4 sF[TT + SF_PAD];          // packed forcings {p,tm,ld,0}
  // Output buffers in LDS (r14 win): no global stores -> no vmcnt(0) drain at
  // the per-step barriers. Flushed once after the loop. ~104 KB total LDS.
  __shared__ float sQ[TT], sS0[TT], sS1[TT];

  const int tid = threadIdx.x;
  const int lane = tid & 63;
  const int w = tid >> 6;          // wave 0..3
  const int li = lane & 15;        // MFMA col within tile
  const int g = lane >> 4;         // k-group 0..3
  const int jb = 64 * w + 4 * li;  // this lane's 4 MFMA j's: jb+0..3
  const int j0 = 64 * w + lane;    // this lane's single layer-0 j

  // ---- stage packed forcings ----
  for (int i = tid; i < TT; i += 256) {
    f32x4 F = {gin[5 * i + 2], gin[5 * i + 3], gdayl[i], 0.0f};
    sF[i] = F;
  }
  if (tid < SF_PAD) {
    f32x4 Z = {0.f, 0.f, 0.f, 0.f};
    sF[TT + tid] = Z;  // t+1 prefetch at t=TT-1 reads defined data
  }
  if (tid < 64) sWP[tid] = 0.0f;   // slots >=20 stay 0 forever

  // ---- per-thread constants ----
  float s0 = gin[0], s1 = gin[1];
  const float bo0 = gbout[0], bo1 = gbout[1], bo2 = gbout[2], bo3 = gbout[3],
              bo4 = gbout[4];
  // layer-0 consts for this lane's single j0 (L0 lane->j map is free)
  const float w00J = gW0[j0], w01J = gW0[HH + j0], w02J = gW0[2 * HH + j0],
              w03J = gW0[3 * HH + j0], b0J = gb0[j0];
  // per-chain consts (j = jb + c): biases pre-scaled for accumulator C-init
#define CDECL(c)                                                               \
  const float b1s_##c = gb1[jb + (c)] * WSCALE,                                \
              b2s_##c = gb2[jb + (c)] * WSCALE,                                \
              wo0_##c = gWout[5 * (jb + (c)) + 0],                             \
              wo1_##c = gWout[5 * (jb + (c)) + 1],                             \
              wo2_##c = gWout[5 * (jb + (c)) + 2],                             \
              wo3_##c = gWout[5 * (jb + (c)) + 3],                             \
              wo4_##c = gWout[5 * (jb + (c)) + 4];
  REPC(CDECL)
#undef CDECL

  // ---- weight B-fragments -> AGPRs (native MFMA operands, r10-proven).
  // Fragment (layer L, chain c, slice i): lane holds B[k][col=li] with
  // k = 32i + 8g + e, column j = jb + c.
#define FDECL(i) f16x8 a1_0_##i, a1_1_##i, a1_2_##i, a1_3_##i,                 \
                       a2_0_##i, a2_1_##i, a2_2_##i, a2_3_##i;
  REP8(FDECL)
#undef FDECL
#define MK(dst, G, i, c)                                                       \
  {                                                                            \
    const float* p = (G) + (32 * (i) + g * 8) * HH + jb + (c);                 \
    f16x8 f;                                                                   \
    f[0] = (_Float16)(p[0] * WSCALE);      f[1] = (_Float16)(p[HH] * WSCALE);  \
    f[2] = (_Float16)(p[2 * HH] * WSCALE); f[3] = (_Float16)(p[3 * HH] * WSCALE); \
    f[4] = (_Float16)(p[4 * HH] * WSCALE); f[5] = (_Float16)(p[5 * HH] * WSCALE); \
    f[6] = (_Float16)(p[6 * HH] * WSCALE); f[7] = (_Float16)(p[7 * HH] * WSCALE); \
    dst = f;                                                                   \
    asm volatile("" : "+a"(dst));                                              \
  }
#define FINIT(i)                                                               \
  MK(a1_0_##i, gW1, i, 0) MK(a1_1_##i, gW1, i, 1)                              \
  MK(a1_2_##i, gW1, i, 2) MK(a1_3_##i, gW1, i, 3)                              \
  MK(a2_0_##i, gW2, i, 0) MK(a2_1_##i, gW2, i, 1)                              \
  MK(a2_2_##i, gW2, i, 2) MK(a2_3_##i, gW2, i, 3)
  REP8(FINIT)
#undef FINIT
#undef MK

  const char* hp0 = (const char*)h0l + g * 16;  // A-fill base (k-group window)
  const char* hp1 = (const char*)h1l + g * 16;

  // Non-volatile MFMA (r12/r13 evidence: compiler schedules ds_read/MFMA
  // interleave better than source pinning).
#define MFMA(acc, a, b)                                                        \
  asm("v_mfma_f32_16x16x32_f16 %0, %1, %2, %0" : "+v"(acc) : "v"(a), "a"(b));

  __syncthreads();  // staging + sWP zero visible

  f32x4 Fc = sF[0];
  // forcing part of layer-0's z, computed one step ahead (off critical path)
  float z0f = b0J + Fc[0] * w02J + Fc[1] * w03J;
  for (int t = 0; t < TT; ++t) {
    const float tm = Fc[1];
    const float ld = Fc[2];

    // ---- layer 0: ONE j per lane; only the state-dependent 2 FMA + tanh
    // sit after the state update on the serial path ----
    float h0J = xtanh(z0f + s0 * w00J + s1 * w01J);
    h0l[j0] = (_Float16)h0J;
    __syncthreads();  // A

    f32x4 Fn = sF[t + 1];  // prefetch next forcings; hides under layer-1 MFMAs
    float z0fN = b0J + Fn[0] * w02J + Fn[1] * w03J;  // next step's forcing part

    // ---- layer 1: 32 MFMA on 4 independent chains; bias pre-loaded in C ----
    f32x4 d0 = {b1s_0, 0.f, 0.f, 0.f}, d1 = {b1s_1, 0.f, 0.f, 0.f};
    f32x4 d2 = {b1s_2, 0.f, 0.f, 0.f}, d3 = {b1s_3, 0.f, 0.f, 0.f};
    asm volatile("s_nop 1" : "+v"(d0), "+v"(d1), "+v"(d2), "+v"(d3));
#define MM1(i)                                                                 \
  {                                                                            \
    f16x8 av = *(const f16x8*)(hp0 + (i) * 64);                                \
    MFMA(d0, av, a1_0_##i) MFMA(d1, av, a1_1_##i)                              \
    MFMA(d2, av, a1_2_##i) MFMA(d3, av, a1_3_##i)                              \
  }
    REP8(MM1)
#undef MM1
    asm volatile("s_nop 7\n\ts_nop 7" : "+v"(d0), "+v"(d1), "+v"(d2), "+v"(d3));
#define H1C(c) float h1_##c = xtanh_ds(d##c[0]);
    REPC(H1C)
#undef H1C
    if (lane < 16) {
      f16x4 hv = {(_Float16)h1_0, (_Float16)h1_1, (_Float16)h1_2,
                  (_Float16)h1_3};
      *(f16x4*)((char*)h1l + (jb << 1)) = hv;
    }
    __syncthreads();  // B

    // ---- layer 2 (same schedule) ----
    f32x4 e0 = {b2s_0, 0.f, 0.f, 0.f}, e1 = {b2s_1, 0.f, 0.f, 0.f};
    f32x4 e2 = {b2s_2, 0.f, 0.f, 0.f}, e3 = {b2s_3, 0.f, 0.f, 0.f};
    asm volatile("s_nop 1" : "+v"(e0), "+v"(e1), "+v"(e2), "+v"(e3));
#define MM2(i)                                                                 \
  {                                                                            \
    f16x8 av = *(const f16x8*)(hp1 + (i) * 64);                                \
    MFMA(e0, av, a2_0_##i) MFMA(e1, av, a2_1_##i)                              \
    MFMA(e2, av, a2_2_##i) MFMA(e3, av, a2_3_##i)                              \
  }
    REP8(MM2)
#undef MM2
    asm volatile("s_nop 7\n\ts_nop 7" : "+v"(e0), "+v"(e1), "+v"(e2), "+v"(e3));
#define H2C(c) float h2_##c = xtanh_ds(e##c[0]);
    REPC(H2C)
#undef H2C

    // ---- output layer: per-lane partials over 4 j's, DPP row all-reduce ----
    float p0 = h2_0 * wo0_0 + h2_1 * wo0_1 + h2_2 * wo0_2 + h2_3 * wo0_3;
    float p1 = h2_0 * wo1_0 + h2_1 * wo1_1 + h2_2 * wo1_2 + h2_3 * wo1_3;
    float p2 = h2_0 * wo2_0 + h2_1 * wo2_1 + h2_2 * wo2_2 + h2_3 * wo2_3;
    float p3 = h2_0 * wo3_0 + h2_1 * wo3_1 + h2_2 * wo3_2 + h2_3 * wo3_3;
    float p4 = h2_0 * wo4_0 + h2_1 * wo4_1 + h2_2 * wo4_2 + h2_3 * wo4_3;
    DPPADD(p0, 0x121) DPPADD(p0, 0x122) DPPADD(p0, 0x124) DPPADD(p0, 0x128)
    DPPADD(p1, 0x121) DPPADD(p1, 0x122) DPPADD(p1, 0x124) DPPADD(p1, 0x128)
    DPPADD(p2, 0x121) DPPADD(p2, 0x122) DPPADD(p2, 0x124) DPPADD(p2, 0x128)
    DPPADD(p3, 0x121) DPPADD(p3, 0x122) DPPADD(p3, 0x124) DPPADD(p3, 0x128)
    DPPADD(p4, 0x121) DPPADD(p4, 0x122) DPPADD(p4, 0x124) DPPADD(p4, 0x128)
    // every lane now holds the wave's 64-j sums; lane m (<5) writes slot m*4+w
    float pv = lane == 0 ? p0 : lane == 1 ? p1 : lane == 2 ? p2
                                          : lane == 3 ? p3 : p4;
    if (lane < 5) sWP[lane * 4 + w] = pv;
    __syncthreads();  // C

    // ---- finalize on ALL threads: quad-xor reduce over w, transforms ----
    float v = sWP[lane];  // lane l: m = l>>2, w = l&3 (slots >=20 are 0)
    DPPADD(v, 0xB1)       // quad_perm xor1
    DPPADD(v, 0x4E)       // quad_perm xor2 -> all 4 lanes of quad m hold o_m
    float o0 = RDLANE(v, 0) + bo0;
    float o1 = RDLANE(v, 4) + bo1;
    float o2 = RDLANE(v, 8) + bo2;
    float o3 = RDLANE(v, 12) + bo3;
    float o4 = RDLANE(v, 16) + bo4;
    if (tid == 64) {  // wave 1 buffers outputs in LDS (wave 0 owns sWP)
      sQ[t] = o4;           // q_output[t] = raw mlp output m=4 at state_t
      sS0[t] = s0;          // s_snow_nn[t] (pre-update)
      sS1[t] = s1;          // s_water_nn[t]
    }
    float sh0 = xsinh(o0), sh1 = xsinh(o1), sh2 = xsinh(o2);
    float e3x = xexp(o3), e4x = xexp(o4);
    float stn = xstep(-tm), st0 = xstep(s0), st1 = xstep(s1);
    float psn = fmaxf(sh0 * stn, 0.0f);
    float prn = fmaxf(sh1, 0.0f);
    float mm = fmaxf(st0 * sh2, 0.0f);
    float evt = st1 * e3x * ld;
    float qq = st1 * e4x;
    s0 += psn - mm;                 // DT = 1
    s1 += prn + mm - evt - qq;
    Fc = Fn;
    z0f = z0fN;
  }
#undef MFMA

  // ---- flush buffered outputs to global (coalesced) ----
  __syncthreads();
  for (int i = tid; i < TT; i += 256) {
    gout[i] = sQ[i];
    gout[TT + i] = sS0[i];
    gout[2 * TT + i] = sS1[i];
  }
}

extern "C" void kernel_launch(void* const* d_in, const int* in_sizes, int n_in,
                              void* d_out, int out_size, void* d_ws, size_t ws_size,
                              hipStream_t stream) {
  const float* gin   = (const float*)d_in[0];
  const float* gdayl = (const float*)d_in[1];
  const float* gW0   = (const float*)d_in[2];
  const float* gb0   = (const float*)d_in[3];
  const float* gW1   = (const float*)d_in[4];
  const float* gb1   = (const float*)d_in[5];
  const float* gW2   = (const float*)d_in[6];
  const float* gb2   = (const float*)d_in[7];
  const float* gWout = (const float*)d_in[8];
  const float* gbout = (const float*)d_in[9];
  float* gout = (float*)d_out;
  exphydro_scan<<<dim3(1), dim3(256), 0, stream>>>(
      gin, gdayl, gW0, gb0, gW1, gb1, gW2, gb2, gWout, gbout, gout);
}

// Round 19
// 4586.073 us; speedup vs baseline: 1.4326x; 1.0708x over previous
//
#include <hip/hip_runtime.h>
#include <hip/hip_bf16.h>

#define TT 3650
#define HH 256

typedef _Float16 f16x4 __attribute__((ext_vector_type(4)));
typedef _Float16 f16x8 __attribute__((ext_vector_type(8)));
typedef float f32x4 __attribute__((ext_vector_type(4)));

__device__ __forceinline__ float xexp2(float x) { return __builtin_amdgcn_exp2f(x); }
__device__ __forceinline__ float xrcp(float x) { return __builtin_amdgcn_rcpf(x); }
__device__ __forceinline__ float xexp(float x) { return xexp2(x * 1.4426950408889634f); }
__device__ __forceinline__ float xtanh(float x) {
  float e = xexp2(x * 2.8853900817779268f);  // e^{2x}
  return 1.0f - 2.0f * xrcp(e + 1.0f);
}
// tanh(d * 2^-10): descale fused into the exp2 constant (one mul, not two)
__device__ __forceinline__ float xtanh_ds(float d) {
  float e = xexp2(d * 0.0028177637517362566f);  // 2.88539../1024
  return 1.0f - 2.0f * xrcp(e + 1.0f);
}
__device__ __forceinline__ float xstep(float x) {  // sigmoid(10x)
  return xrcp(1.0f + xexp2(-14.426950408889634f * x));
}
__device__ __forceinline__ float xsinh(float x) {
  float e = xexp(x);
  return 0.5f * (e - xrcp(e));
}

#define DPPADD(x, ctrl)                                                        \
  (x) += __builtin_bit_cast(float, __builtin_amdgcn_update_dpp(                \
            0, __builtin_bit_cast(int, (x)), (ctrl), 0xf, 0xf, false));
#define RDLANE(x, l)                                                           \
  __builtin_bit_cast(float,                                                    \
      __builtin_amdgcn_readlane(__builtin_bit_cast(int, (x)), (l)))

#define REP8(M) M(0) M(1) M(2) M(3) M(4) M(5) M(6) M(7)
#define REPC(M) M(0) M(1) M(2) M(3)

// Weights stored as fp16 of (W * 2^10): avoids fp16-denormal weights, which
// the MFMA pipe flushes (round-9 drift). Descale fused into xtanh_ds.
#define WSCALE 1024.0f

#define SF_PAD 2

__global__ void __launch_bounds__(256, 1) exphydro_scan(
    const float* __restrict__ gin, const float* __restrict__ gdayl,
    const float* __restrict__ gW0, const float* __restrict__ gb0,
    const float* __restrict__ gW1, const float* __restrict__ gb1,
    const float* __restrict__ gW2, const float* __restrict__ gb2,
    const float* __restrict__ gWout, const float* __restrict__ gbout,
    float* __restrict__ gout) {
  __shared__ alignas(16) _Float16 h0l[HH];   // 512 B activation buffers
  __shared__ alignas(16) _Float16 h1l[HH];
  __shared__ float sWP[64];                  // [m][w]: slot m*4+w, 20 used
  __shared__ f32x4 sF[TT + SF_PAD];          // packed forcings {p,tm,ld,0}
  // Output buffers in LDS (r14 win): no global stores -> no vmcnt(0) drain at
  // the per-step barriers. Flushed once after the loop. ~104 KB total LDS.
  __shared__ float sQ[TT], sS0[TT], sS1[TT];

  const int tid = threadIdx.x;
  const int lane = tid & 63;
  const int w = tid >> 6;          // wave 0..3
  const int li = lane & 15;        // MFMA col within tile
  const int g = lane >> 4;         // k-group 0..3
  const int jb = 64 * w + 4 * li;  // this lane's 4 MFMA j's: jb+0..3
  const int j0 = 64 * w + lane;    // this lane's single layer-0 j

  // ---- stage packed forcings ----
  for (int i = tid; i < TT; i += 256) {
    f32x4 F = {gin[5 * i + 2], gin[5 * i + 3], gdayl[i], 0.0f};
    sF[i] = F;
  }
  if (tid < SF_PAD) {
    f32x4 Z = {0.f, 0.f, 0.f, 0.f};
    sF[TT + tid] = Z;  // t+1 prefetch at t=TT-1 reads defined data
  }
  if (tid < 64) sWP[tid] = 0.0f;   // slots >=20 stay 0 forever

  // ---- per-thread constants ----
  float s0 = gin[0], s1 = gin[1];
  const float bo0 = gbout[0], bo1 = gbout[1], bo2 = gbout[2], bo3 = gbout[3],
              bo4 = gbout[4];
  // layer-0 consts for this lane's single j0 (L0 lane->j map is free)
  const float w00J = gW0[j0], w01J = gW0[HH + j0], w02J = gW0[2 * HH + j0],
              w03J = gW0[3 * HH + j0], b0J = gb0[j0];
  // per-chain consts (j = jb + c): biases pre-scaled for accumulator C-init
#define CDECL(c)                                                               \
  const float b1s_##c = gb1[jb + (c)] * WSCALE,                                \
              b2s_##c = gb2[jb + (c)] * WSCALE,                                \
              wo0_##c = gWout[5 * (jb + (c)) + 0],                             \
              wo1_##c = gWout[5 * (jb + (c)) + 1],                             \
              wo2_##c = gWout[5 * (jb + (c)) + 2],                             \
              wo3_##c = gWout[5 * (jb + (c)) + 3],                             \
              wo4_##c = gWout[5 * (jb + (c)) + 4];
  REPC(CDECL)
#undef CDECL

  // ---- weight B-fragments -> AGPRs (native MFMA operands, r10-proven).
  // Fragment (layer L, chain c, slice i): lane holds B[k][col=li] with
  // k = 32i + 8g + e, column j = jb + c.
#define FDECL(i) f16x8 a1_0_##i, a1_1_##i, a1_2_##i, a1_3_##i,                 \
                       a2_0_##i, a2_1_##i, a2_2_##i, a2_3_##i;
  REP8(FDECL)
#undef FDECL
#define MK(dst, G, i, c)                                                       \
  {                                                                            \
    const float* p = (G) + (32 * (i) + g * 8) * HH + jb + (c);                 \
    f16x8 f;                                                                   \
    f[0] = (_Float16)(p[0] * WSCALE);      f[1] = (_Float16)(p[HH] * WSCALE);  \
    f[2] = (_Float16)(p[2 * HH] * WSCALE); f[3] = (_Float16)(p[3 * HH] * WSCALE); \
    f[4] = (_Float16)(p[4 * HH] * WSCALE); f[5] = (_Float16)(p[5 * HH] * WSCALE); \
    f[6] = (_Float16)(p[6 * HH] * WSCALE); f[7] = (_Float16)(p[7 * HH] * WSCALE); \
    dst = f;                                                                   \
    asm volatile("" : "+a"(dst));                                              \
  }
#define FINIT(i)                                                               \
  MK(a1_0_##i, gW1, i, 0) MK(a1_1_##i, gW1, i, 1)                              \
  MK(a1_2_##i, gW1, i, 2) MK(a1_3_##i, gW1, i, 3)                              \
  MK(a2_0_##i, gW2, i, 0) MK(a2_1_##i, gW2, i, 1)                              \
  MK(a2_2_##i, gW2, i, 2) MK(a2_3_##i, gW2, i, 3)
  REP8(FINIT)
#undef FINIT
#undef MK

  const char* hp0 = (const char*)h0l + g * 16;  // A-fill base (k-group window)
  const char* hp1 = (const char*)h1l + g * 16;

  // Non-volatile MFMA (r12/r13 evidence: compiler schedules ds_read/MFMA
  // interleave better than source pinning).
#define MFMA(acc, a, b)                                                        \
  asm("v_mfma_f32_16x16x32_f16 %0, %1, %2, %0" : "+v"(acc) : "v"(a), "a"(b));

  __syncthreads();  // staging + sWP zero visible

  f32x4 Fc = sF[0];
  for (int t = 0; t < TT; ++t) {
    const float p_in = Fc[0];
    const float tm = Fc[1];
    const float ld = Fc[2];

    // ---- layer 0: ONE j per lane (64 lanes x 4 waves = 256 j's, no
    // redundancy -> 1 tanh instead of 4); b16 write, 2-way dword share free ----
    float h0J = xtanh(b0J + s0 * w00J + s1 * w01J + p_in * w02J + tm * w03J);
    h0l[j0] = (_Float16)h0J;
    __syncthreads();  // A

    f32x4 Fn = sF[t + 1];  // prefetch next forcings; hides under layer-1 MFMAs

    // ---- layer 1: 32 MFMA on 4 independent chains; bias pre-loaded in C ----
    f32x4 d0 = {b1s_0, 0.f, 0.f, 0.f}, d1 = {b1s_1, 0.f, 0.f, 0.f};
    f32x4 d2 = {b1s_2, 0.f, 0.f, 0.f}, d3 = {b1s_3, 0.f, 0.f, 0.f};
    asm volatile("s_nop 1" : "+v"(d0), "+v"(d1), "+v"(d2), "+v"(d3));
#define MM1(i)                                                                 \
  {                                                                            \
    f16x8 av = *(const f16x8*)(hp0 + (i) * 64);                                \
    MFMA(d0, av, a1_0_##i) MFMA(d1, av, a1_1_##i)                              \
    MFMA(d2, av, a1_2_##i) MFMA(d3, av, a1_3_##i)                              \
  }
    REP8(MM1)
#undef MM1
    asm volatile("s_nop 7\n\ts_nop 7" : "+v"(d0), "+v"(d1), "+v"(d2), "+v"(d3));
#define H1C(c) float h1_##c = xtanh_ds(d##c[0]);
    REPC(H1C)
#undef H1C
    if (lane < 16) {
      f16x4 hv = {(_Float16)h1_0, (_Float16)h1_1, (_Float16)h1_2,
                  (_Float16)h1_3};
      *(f16x4*)((char*)h1l + (jb << 1)) = hv;
    }
    __syncthreads();  // B

    // ---- layer 2 (same schedule) ----
    f32x4 e0 = {b2s_0, 0.f, 0.f, 0.f}, e1 = {b2s_1, 0.f, 0.f, 0.f};
    f32x4 e2 = {b2s_2, 0.f, 0.f, 0.f}, e3 = {b2s_3, 0.f, 0.f, 0.f};
    asm volatile("s_nop 1" : "+v"(e0), "+v"(e1), "+v"(e2), "+v"(e3));
#define MM2(i)                                                                 \
  {                                                                            \
    f16x8 av = *(const f16x8*)(hp1 + (i) * 64);                                \
    MFMA(e0, av, a2_0_##i) MFMA(e1, av, a2_1_##i)                              \
    MFMA(e2, av, a2_2_##i) MFMA(e3, av, a2_3_##i)                              \
  }
    REP8(MM2)
#undef MM2
    asm volatile("s_nop 7\n\ts_nop 7" : "+v"(e0), "+v"(e1), "+v"(e2), "+v"(e3));
#define H2C(c) float h2_##c = xtanh_ds(e##c[0]);
    REPC(H2C)
#undef H2C

    // ---- output layer: per-lane partials over 4 j's, DPP row all-reduce ----
    float p0 = h2_0 * wo0_0 + h2_1 * wo0_1 + h2_2 * wo0_2 + h2_3 * wo0_3;
    float p1 = h2_0 * wo1_0 + h2_1 * wo1_1 + h2_2 * wo1_2 + h2_3 * wo1_3;
    float p2 = h2_0 * wo2_0 + h2_1 * wo2_1 + h2_2 * wo2_2 + h2_3 * wo2_3;
    float p3 = h2_0 * wo3_0 + h2_1 * wo3_1 + h2_2 * wo3_2 + h2_3 * wo3_3;
    float p4 = h2_0 * wo4_0 + h2_1 * wo4_1 + h2_2 * wo4_2 + h2_3 * wo4_3;
    DPPADD(p0, 0x121) DPPADD(p0, 0x122) DPPADD(p0, 0x124) DPPADD(p0, 0x128)
    DPPADD(p1, 0x121) DPPADD(p1, 0x122) DPPADD(p1, 0x124) DPPADD(p1, 0x128)
    DPPADD(p2, 0x121) DPPADD(p2, 0x122) DPPADD(p2, 0x124) DPPADD(p2, 0x128)
    DPPADD(p3, 0x121) DPPADD(p3, 0x122) DPPADD(p3, 0x124) DPPADD(p3, 0x128)
    DPPADD(p4, 0x121) DPPADD(p4, 0x122) DPPADD(p4, 0x124) DPPADD(p4, 0x128)
    // every lane now holds the wave's 64-j sums; lane m (<5) writes slot m*4+w
    float pv = lane == 0 ? p0 : lane == 1 ? p1 : lane == 2 ? p2
                                          : lane == 3 ? p3 : p4;
    if (lane < 5) sWP[lane * 4 + w] = pv;
    __syncthreads();  // C

    // ---- finalize on ALL threads: quad-xor reduce over w, transforms ----
    float v = sWP[lane];  // lane l: m = l>>2, w = l&3 (slots >=20 are 0)
    DPPADD(v, 0xB1)       // quad_perm xor1
    DPPADD(v, 0x4E)       // quad_perm xor2 -> all 4 lanes of quad m hold o_m
    float o0 = RDLANE(v, 0) + bo0;
    float o1 = RDLANE(v, 4) + bo1;
    float o2 = RDLANE(v, 8) + bo2;
    float o3 = RDLANE(v, 12) + bo3;
    float o4 = RDLANE(v, 16) + bo4;
    if (tid == 64) {  // wave 1 buffers outputs in LDS (wave 0 owns sWP)
      sQ[t] = o4;           // q_output[t] = raw mlp output m=4 at state_t
      sS0[t] = s0;          // s_snow_nn[t] (pre-update)
      sS1[t] = s1;          // s_water_nn[t]
    }
    float sh0 = xsinh(o0), sh1 = xsinh(o1), sh2 = xsinh(o2);
    float e3x = xexp(o3), e4x = xexp(o4);
    float stn = xstep(-tm), st0 = xstep(s0), st1 = xstep(s1);
    float psn = fmaxf(sh0 * stn, 0.0f);
    float prn = fmaxf(sh1, 0.0f);
    float mm = fmaxf(st0 * sh2, 0.0f);
    float evt = st1 * e3x * ld;
    float qq = st1 * e4x;
    s0 += psn - mm;                 // DT = 1
    s1 += prn + mm - evt - qq;
    Fc = Fn;
  }
#undef MFMA

  // ---- flush buffered outputs to global (coalesced) ----
  __syncthreads();
  for (int i = tid; i < TT; i += 256) {
    gout[i] = sQ[i];
    gout[TT + i] = sS0[i];
    gout[2 * TT + i] = sS1[i];
  }
}

extern "C" void kernel_launch(void* const* d_in, const int* in_sizes, int n_in,
                              void* d_out, int out_size, void* d_ws, size_t ws_size,
                              hipStream_t stream) {
  const float* gin   = (const float*)d_in[0];
  const float* gdayl = (const float*)d_in[1];
  const float* gW0   = (const float*)d_in[2];
  const float* gb0   = (const float*)d_in[3];
  const float* gW1   = (const float*)d_in[4];
  const float* gb1   = (const float*)d_in[5];
  const float* gW2   = (const float*)d_in[6];
  const float* gb2   = (const float*)d_in[7];
  const float* gWout = (const float*)d_in[8];
  const float* gbout = (const float*)d_in[9];
  float* gout = (float*)d_out;
  exphydro_scan<<<dim3(1), dim3(256), 0, stream>>>(
      gin, gdayl, gW0, gb0, gW1, gb1, gW2, gb2, gWout, gbout, gout);
}